// Round 5
// baseline (331.939 us; speedup 1.0000x reference)
//
#include <hip/hip_runtime.h>

// TripletAngularMarginLoss: bs=16384, d=64 (== number of classes)
// out = mean(relu(0.5 + ap - an)) + mean(relu(0.8-ap)) + mean(relu(an-0.4)) + CE
// ap[i] = min_{t[j]==t[i]} cos(x_i,x_j), an[i] = max_{t[j]!=t[i]} cos(x_i,x_j)
//
// R2: class-sort rows -> pure-negative fast path (1 max/entry).
// R4 post-mortem: mine 10x over issue floor (compiler un-batched loads at
//   VGPR=76; 4x redundant per-wave B loads; no latency hiding) and ~90us of
//   small-kernel/launch overhead. R5: LDS double-buffered B staging shared by
//   the block + fuse to 5 graph nodes (finalize folded into mine, last-block).

#define N_ROWS 16384
#define N_DIM 64

typedef __attribute__((ext_vector_type(8))) short bf16x8;
typedef __attribute__((ext_vector_type(4))) float f32x4;

__device__ inline unsigned short f2bf(float f) {
  unsigned u = __float_as_uint(f);
  unsigned r = u + 0x7fffu + ((u >> 16) & 1u);   // round-to-nearest-even
  return (unsigned short)(r >> 16);
}

// order-preserving float->uint encoding for atomicMin/atomicMax
__device__ inline unsigned enc_key(float f) {
  unsigned u = __float_as_uint(f);
  return (u & 0x80000000u) ? ~u : (u | 0x80000000u);
}
__device__ inline float dec_key(unsigned k) {
  unsigned u = (k & 0x80000000u) ? (k ^ 0x80000000u) : ~k;
  return __uint_as_float(u);
}

// ---------------- K1: class histogram + min/max key init (64 blocks) --------
__global__ void hist_kernel(const int* __restrict__ tgt, int* __restrict__ hist,
                            unsigned* __restrict__ mp_key, unsigned* __restrict__ mn_key) {
  __shared__ int h[64];
  const int i = blockIdx.x * 256 + threadIdx.x;
  mp_key[i] = 0xFFFFFFFFu;                        // +inf key for min
  mn_key[i] = 0u;                                 // -inf key for max
  if (threadIdx.x < 64) h[threadIdx.x] = 0;
  __syncthreads();
  atomicAdd(&h[tgt[i]], 1);
  __syncthreads();
  if (threadIdx.x < 64 && h[threadIdx.x]) atomicAdd(&hist[threadIdx.x], h[threadIdx.x]);
}

// ---------------- K2: scan (per-block, redundant) + scatter + prep ----------
// 1024 blocks x 256 threads; block handles 16 rows (4 waves x 4 rows).
__global__ void prep_kernel(const float* __restrict__ x, const int* __restrict__ tgt,
                            const int* __restrict__ hist, int* __restrict__ cursor,
                            int* __restrict__ class_start,
                            unsigned short* __restrict__ xs, int* __restrict__ ts,
                            float* __restrict__ ce_row) {
  __shared__ int cs[64];
  const int tid  = threadIdx.x;
  const int lane = tid & 63;
  // exclusive prefix over the 64-class histogram (wave 0 only)
  if (tid < 64) {
    const int hv = hist[tid];
    int s = hv;
#pragma unroll
    for (int d = 1; d < 64; d <<= 1) {
      int t = __shfl_up(s, d, 64);
      if (tid >= d) s += t;
    }
    cs[tid] = s - hv;
    if (blockIdx.x == 0) {                 // publish for mine_kernel
      class_start[tid] = s - hv;
      if (tid == 63) class_start[64] = s;
    }
  }
  __syncthreads();

#pragma unroll
  for (int p = 0; p < 4; ++p) {
    const int r = blockIdx.x * 16 + (tid >> 6) * 4 + p;
    float v  = x[r * N_DIM + lane];
    float ss = v * v;
#pragma unroll
    for (int s = 1; s < 64; s <<= 1) ss += __shfl_xor(ss, s, 64);
    const float xn = v * rsqrtf(ss);

    // log-softmax CE contribution
    float mx = xn;
#pragma unroll
    for (int s = 1; s < 64; s <<= 1) mx = fmaxf(mx, __shfl_xor(mx, s, 64));
    float e  = __expf(xn - mx);
    float se = e;
#pragma unroll
    for (int s = 1; s < 64; s <<= 1) se += __shfl_xor(se, s, 64);
    const float lse = mx + __logf(se);
    const int   c   = tgt[r];                     // wave-uniform
    const float xt  = __shfl(xn, c, 64);

    int pos = 0;
    if (lane == 0) pos = cs[c] + atomicAdd(&cursor[c], 1);
    pos = __shfl(pos, 0, 64);
    xs[pos * N_DIM + lane] = f2bf(xn);
    if (lane == 0) { ts[pos] = c; ce_row[r] = lse - xt; }
  }
}

// ---------------- K3: MFMA similarity + hard mining + fused finalize --------
// grid = 64 iblk x 32 jspl = 2048 blocks x 256 threads (4 waves).
// Block: rows iblk*256..+255, cols jspl*512..+511 in 8 double-buffered 64-col
// LDS tiles (plane-major layout: LDS16B[chunk*64 + col], conflict-free b128).
__global__ void __launch_bounds__(256)
mine_kernel(const unsigned short* __restrict__ xs, const int* __restrict__ ts,
            const int* __restrict__ class_start, const float* __restrict__ ce_row,
            unsigned* __restrict__ mp_key, unsigned* __restrict__ mn_key,
            unsigned* __restrict__ done, float* __restrict__ out) {
  __shared__ short tile[2][4096];                  // 2 x 8KB B-tiles
  __shared__ float red[4][4];
  __shared__ int   is_last;

  const int tid     = threadIdx.x;
  const int lane    = tid & 63;
  const int wv      = tid >> 6;
  const int iblk    = blockIdx.x >> 5;
  const int jspl    = blockIdx.x & 31;
  const int rowbase = iblk * 256 + wv * 64;
  const int jbase   = jspl * 512;
  const int m = lane & 15, q = lane >> 4;

  // A fragments: lane holds row (rowbase+tr*16+m), k-chunks q and q+4
  bf16x8 a[4][2];
#pragma unroll
  for (int tr = 0; tr < 4; ++tr) {
    const unsigned short* p = xs + (rowbase + tr * 16 + m) * N_DIM + q * 8;
    a[tr][0] = *(const bf16x8*)(p);
    a[tr][1] = *(const bf16x8*)(p + 32);
  }
  // classes of this lane's C/D rows (row = tr*16 + q*4 + r), slow path only
  int ti[16];
#pragma unroll
  for (int tr = 0; tr < 4; ++tr)
#pragma unroll
    for (int r = 0; r < 4; ++r)
      ti[tr * 4 + r] = ts[rowbase + tr * 16 + q * 4 + r];

  // positive-column interval for ALL rows of this wave (rows sorted by class)
  const int lo = class_start[ts[rowbase]];
  const int hi = class_start[ts[rowbase + 63] + 1];

  float mp[16], mn[16];
#pragma unroll
  for (int k = 0; k < 16; ++k) { mp[k] = __builtin_inff(); mn[k] = -__builtin_inff(); }
  const f32x4 fz = {0.f, 0.f, 0.f, 0.f};

  // LDS staging helpers (plane-major: 16B unit index = chunk*64 + col)
  bf16x8* const L0 = (bf16x8*)&tile[0][0];
  bf16x8* const L1 = (bf16x8*)&tile[1][0];
  const int w0 = ((tid & 7) * 64) + (tid >> 3);          // dest of 16B chunk g=tid
  const int w1 = ((tid & 7) * 64) + 32 + (tid >> 3);     // dest of chunk g=tid+256

  // prologue: stage tile 0
  {
    const bf16x8* g = (const bf16x8*)(xs + (size_t)jbase * N_DIM);
    bf16x8 r0 = g[tid], r1 = g[tid + 256];
    L0[w0] = r0; L0[w1] = r1;
  }
  __syncthreads();

  for (int it = 0; it < 8; ++it) {
    bf16x8* const Lc = (it & 1) ? L1 : L0;
    bf16x8* const Ln = (it & 1) ? L0 : L1;
    bf16x8 r0, r1;
    if (it < 7) {                                   // issue next tile's loads
      const bf16x8* g = (const bf16x8*)(xs + (size_t)(jbase + (it + 1) * 64) * N_DIM);
      r0 = g[tid]; r1 = g[tid + 256];
    }
    const int jb0 = jbase + it * 64;
#pragma unroll
    for (int tc = 0; tc < 4; ++tc) {
      const int col = tc * 16 + m;                  // tile-local output column
      const bf16x8 b0 = Lc[q * 64 + col];
      const bf16x8 b1 = Lc[(q + 4) * 64 + col];
      const int jb = jb0 + tc * 16;
      if ((jb < hi) && (jb + 16 > lo)) {            // wave-uniform slow path
        const int ctj = ts[jb + m];
#pragma unroll
        for (int tr = 0; tr < 4; ++tr) {
          f32x4 acc = __builtin_amdgcn_mfma_f32_16x16x32_bf16(a[tr][0], b0, fz, 0, 0, 0);
          acc = __builtin_amdgcn_mfma_f32_16x16x32_bf16(a[tr][1], b1, acc, 0, 0, 0);
#pragma unroll
          for (int r = 0; r < 4; ++r) {
            const bool  pos = (ctj == ti[tr * 4 + r]);
            const float d   = acc[r];
            mp[tr * 4 + r] = fminf(mp[tr * 4 + r], pos ? d : __builtin_inff());
            mn[tr * 4 + r] = fmaxf(mn[tr * 4 + r], pos ? -__builtin_inff() : d);
          }
        }
      } else {                                      // pure-negative fast path
#pragma unroll
        for (int tr = 0; tr < 4; ++tr) {
          f32x4 acc = __builtin_amdgcn_mfma_f32_16x16x32_bf16(a[tr][0], b0, fz, 0, 0, 0);
          acc = __builtin_amdgcn_mfma_f32_16x16x32_bf16(a[tr][1], b1, acc, 0, 0, 0);
#pragma unroll
          for (int r = 0; r < 4; ++r)
            mn[tr * 4 + r] = fmaxf(mn[tr * 4 + r], acc[r]);
        }
      }
    }
    if (it < 7) {
      Ln[w0] = r0; Ln[w1] = r1;                     // safe: Ln last read at it-1
      __syncthreads();
    }
  }

  // reduce across the 16 m-lanes inside each q-group
#pragma unroll
  for (int s = 1; s < 16; s <<= 1) {
#pragma unroll
    for (int k = 0; k < 16; ++k) {
      mp[k] = fminf(mp[k], __shfl_xor(mp[k], s, 64));
      mn[k] = fmaxf(mn[k], __shfl_xor(mn[k], s, 64));
    }
  }
  if (m == 0) {
#pragma unroll
    for (int tr = 0; tr < 4; ++tr)
#pragma unroll
      for (int r = 0; r < 4; ++r) {
        const int row = rowbase + tr * 16 + q * 4 + r;
        atomicMin(&mp_key[row], enc_key(mp[tr * 4 + r]));
        atomicMax(&mn_key[row], enc_key(mn[tr * 4 + r]));
      }
  }

  // ---- fused finalize: last block to finish reduces everything ----
  __threadfence();
  if (tid == 0) is_last = (atomicAdd(done, 1u) == (unsigned)(gridDim.x - 1));
  __syncthreads();
  if (is_last) {
    float s1 = 0.f, s2 = 0.f;
    for (int r = tid; r < N_ROWS; r += 256) {
      const unsigned kp = __hip_atomic_load(&mp_key[r], __ATOMIC_RELAXED, __HIP_MEMORY_SCOPE_AGENT);
      const unsigned kn = __hip_atomic_load(&mn_key[r], __ATOMIC_RELAXED, __HIP_MEMORY_SCOPE_AGENT);
      const float ap = dec_key(kp);
      const float an = dec_key(kn);
      s1 += fmaxf(0.5f + ap - an, 0.f) + fmaxf(0.8f - ap, 0.f) + fmaxf(an - 0.4f, 0.f);
      s2 += ce_row[r];
    }
    float s = s1 + s2;
#pragma unroll
    for (int d = 1; d < 64; d <<= 1) s += __shfl_xor(s, d, 64);
    if (lane == 0) red[0][wv] = s;
    __syncthreads();
    if (tid == 0)
      out[0] = (red[0][0] + red[0][1] + red[0][2] + red[0][3]) * (1.0f / N_ROWS);
  }
}

extern "C" void kernel_launch(void* const* d_in, const int* in_sizes, int n_in,
                              void* d_out, int out_size, void* d_ws, size_t ws_size,
                              hipStream_t stream) {
  const float* x   = (const float*)d_in[0];
  const int*   tgt = (const int*)d_in[1];
  char* ws = (char*)d_ws;

  unsigned short* xs     = (unsigned short*)ws;                           // 2 MB sorted bf16
  unsigned*       mp_key = (unsigned*)(ws + (2u << 20));                  // 64 KB
  unsigned*       mn_key = (unsigned*)(ws + (2u << 20) + (64u << 10));    // 64 KB
  float*          ce_row = (float*)(ws + (2u << 20) + (128u << 10));      // 64 KB
  int*            ts     = (int*)(ws + (2u << 20) + (192u << 10));        // 64 KB
  int*            cstart = (int*)(ws + (2u << 20) + (256u << 10));        // 65*4 B (pad 1KB)
  int*            hist   = (int*)(ws + (2u << 20) + (257u << 10));        // 256 B
  int*            cursor = (int*)(ws + (2u << 20) + (257u << 10) + 256);  // 256 B
  unsigned*       done   = (unsigned*)(ws + (2u << 20) + (257u << 10) + 512); // 4 B
  float*          out    = (float*)d_out;

  // zero hist + cursor + done in one node
  hipMemsetAsync(hist, 0, 1024, stream);

  hist_kernel<<<64, 256, 0, stream>>>(tgt, hist, mp_key, mn_key);
  prep_kernel<<<1024, 256, 0, stream>>>(x, tgt, hist, cursor, cstart, xs, ts, ce_row);
  mine_kernel<<<2048, 256, 0, stream>>>(xs, ts, cstart, ce_row, mp_key, mn_key, done, out);
}

// Round 6
// 326.288 us; speedup vs baseline: 1.0173x; 1.0173x over previous
//
#include <hip/hip_runtime.h>

// TripletAngularMarginLoss: bs=16384, d=64 (== number of classes)
// out = mean(relu(0.5 + ap - an)) + mean(relu(0.8-ap)) + mean(relu(an-0.4)) + CE
// ap[i] = min_{t[j]==t[i]} cos(x_i,x_j), an[i] = max_{t[j]!=t[i]} cos(x_i,x_j)
//
// R2: class-sort rows -> pure-negative fast path (1 max/entry).
// R5 post-mortem: LDS staging layout had 8-way bank conflicts on BOTH write
//   and read (SQ_LDS_BANK_CONFLICT=7.3M, mine 204us). R6: XOR-swizzled LDS
//   unit index idx = col*8 + (chunk ^ (col&7)): write covers full 128B rows
//   per 8 lanes, read spreads q^(m&7) over all 8 bank-quads -> both at the
//   b128 throughput floor. Plus packed row-classes (VGPR) and precomputed
//   per-tc LDS offsets.

#define N_ROWS 16384
#define N_DIM 64

typedef __attribute__((ext_vector_type(8))) short bf16x8;
typedef __attribute__((ext_vector_type(4))) float f32x4;

__device__ inline unsigned short f2bf(float f) {
  unsigned u = __float_as_uint(f);
  unsigned r = u + 0x7fffu + ((u >> 16) & 1u);   // round-to-nearest-even
  return (unsigned short)(r >> 16);
}

// order-preserving float->uint encoding for atomicMin/atomicMax
__device__ inline unsigned enc_key(float f) {
  unsigned u = __float_as_uint(f);
  return (u & 0x80000000u) ? ~u : (u | 0x80000000u);
}
__device__ inline float dec_key(unsigned k) {
  unsigned u = (k & 0x80000000u) ? (k ^ 0x80000000u) : ~k;
  return __uint_as_float(u);
}

// ---------------- K1: class histogram + min/max key init (64 blocks) --------
__global__ void hist_kernel(const int* __restrict__ tgt, int* __restrict__ hist,
                            unsigned* __restrict__ mp_key, unsigned* __restrict__ mn_key) {
  __shared__ int h[64];
  const int i = blockIdx.x * 256 + threadIdx.x;
  mp_key[i] = 0xFFFFFFFFu;                        // +inf key for min
  mn_key[i] = 0u;                                 // -inf key for max
  if (threadIdx.x < 64) h[threadIdx.x] = 0;
  __syncthreads();
  atomicAdd(&h[tgt[i]], 1);
  __syncthreads();
  if (threadIdx.x < 64 && h[threadIdx.x]) atomicAdd(&hist[threadIdx.x], h[threadIdx.x]);
}

// ---------------- K2: scan (per-block, redundant) + scatter + prep ----------
// 1024 blocks x 256 threads; block handles 16 rows (4 waves x 4 rows).
__global__ void prep_kernel(const float* __restrict__ x, const int* __restrict__ tgt,
                            const int* __restrict__ hist, int* __restrict__ cursor,
                            int* __restrict__ class_start,
                            unsigned short* __restrict__ xs, int* __restrict__ ts,
                            float* __restrict__ ce_row) {
  __shared__ int cs[64];
  const int tid  = threadIdx.x;
  const int lane = tid & 63;
  // exclusive prefix over the 64-class histogram (wave 0 only)
  if (tid < 64) {
    const int hv = hist[tid];
    int s = hv;
#pragma unroll
    for (int d = 1; d < 64; d <<= 1) {
      int t = __shfl_up(s, d, 64);
      if (tid >= d) s += t;
    }
    cs[tid] = s - hv;
    if (blockIdx.x == 0) {                 // publish for mine_kernel
      class_start[tid] = s - hv;
      if (tid == 63) class_start[64] = s;
    }
  }
  __syncthreads();

#pragma unroll
  for (int p = 0; p < 4; ++p) {
    const int r = blockIdx.x * 16 + (tid >> 6) * 4 + p;
    float v  = x[r * N_DIM + lane];
    float ss = v * v;
#pragma unroll
    for (int s = 1; s < 64; s <<= 1) ss += __shfl_xor(ss, s, 64);
    const float xn = v * rsqrtf(ss);

    // log-softmax CE contribution
    float mx = xn;
#pragma unroll
    for (int s = 1; s < 64; s <<= 1) mx = fmaxf(mx, __shfl_xor(mx, s, 64));
    float e  = __expf(xn - mx);
    float se = e;
#pragma unroll
    for (int s = 1; s < 64; s <<= 1) se += __shfl_xor(se, s, 64);
    const float lse = mx + __logf(se);
    const int   c   = tgt[r];                     // wave-uniform
    const float xt  = __shfl(xn, c, 64);

    int pos = 0;
    if (lane == 0) pos = cs[c] + atomicAdd(&cursor[c], 1);
    pos = __shfl(pos, 0, 64);
    xs[pos * N_DIM + lane] = f2bf(xn);
    if (lane == 0) { ts[pos] = c; ce_row[r] = lse - xt; }
  }
}

// ---------------- K3: MFMA similarity + hard mining + fused finalize --------
// grid = 64 iblk x 32 jspl = 2048 blocks x 256 threads (4 waves).
// Block: rows iblk*256..+255, cols jspl*512..+511 in 8 double-buffered 64-col
// LDS tiles. Swizzled unit layout: idx = col*8 + (chunk ^ (col&7)).
__global__ void __launch_bounds__(256)
mine_kernel(const unsigned short* __restrict__ xs, const int* __restrict__ ts,
            const int* __restrict__ class_start, const float* __restrict__ ce_row,
            unsigned* __restrict__ mp_key, unsigned* __restrict__ mn_key,
            unsigned* __restrict__ done, float* __restrict__ out) {
  __shared__ short tile[2][4096];                  // 2 x 8KB B-tiles
  __shared__ float red[4];
  __shared__ int   is_last;

  const int tid     = threadIdx.x;
  const int lane    = tid & 63;
  const int wv      = tid >> 6;
  const int iblk    = blockIdx.x >> 5;
  const int jspl    = blockIdx.x & 31;
  const int rowbase = iblk * 256 + wv * 64;
  const int jbase   = jspl * 512;
  const int m = lane & 15, q = lane >> 4;

  // A fragments: lane holds row (rowbase+tr*16+m), k-chunks q and q+4
  bf16x8 a[4][2];
#pragma unroll
  for (int tr = 0; tr < 4; ++tr) {
    const unsigned short* p = xs + (rowbase + tr * 16 + m) * N_DIM + q * 8;
    a[tr][0] = *(const bf16x8*)(p);
    a[tr][1] = *(const bf16x8*)(p + 32);
  }
  // classes of this lane's C/D rows (row = tr*16 + q*4 + r), packed 8b x 4
  int tpack[4];
#pragma unroll
  for (int tr = 0; tr < 4; ++tr) {
    int v = 0;
#pragma unroll
    for (int r = 0; r < 4; ++r)
      v |= ts[rowbase + tr * 16 + q * 4 + r] << (8 * r);
    tpack[tr] = v;
  }

  // positive-column interval for ALL rows of this wave (rows sorted by class)
  const int lo = class_start[ts[rowbase]];
  const int hi = class_start[ts[rowbase + 63] + 1];

  float mp[16], mn[16];
#pragma unroll
  for (int k = 0; k < 16; ++k) { mp[k] = __builtin_inff(); mn[k] = -__builtin_inff(); }
  const f32x4 fz = {0.f, 0.f, 0.f, 0.f};

  bf16x8* const L0 = (bf16x8*)&tile[0][0];
  bf16x8* const L1 = (bf16x8*)&tile[1][0];
  // swizzled write dest for staged chunk g=tid (and g=tid+256 at +256 units)
  const int widx = (tid & ~7) | ((tid & 7) ^ ((tid >> 3) & 7));
  // swizzled read units per tc: col=tc*16+m, chunk=q -> idx; chunk=q+4 -> idx^4
  int ridx[4];
#pragma unroll
  for (int tc = 0; tc < 4; ++tc)
    ridx[tc] = (tc * 16 + m) * 8 + (q ^ (m & 7));

  // prologue: stage tile 0
  {
    const bf16x8* g = (const bf16x8*)(xs + (size_t)jbase * N_DIM);
    bf16x8 r0 = g[tid], r1 = g[tid + 256];
    L0[widx] = r0; L0[widx + 256] = r1;
  }
  __syncthreads();

  for (int it = 0; it < 8; ++it) {
    bf16x8* const Lc = (it & 1) ? L1 : L0;
    bf16x8* const Ln = (it & 1) ? L0 : L1;
    bf16x8 r0, r1;
    if (it < 7) {                                   // issue next tile's loads
      const bf16x8* g = (const bf16x8*)(xs + (size_t)(jbase + (it + 1) * 64) * N_DIM);
      r0 = g[tid]; r1 = g[tid + 256];
    }
    const int jb0 = jbase + it * 64;
#pragma unroll
    for (int tc = 0; tc < 4; ++tc) {
      const bf16x8 b0 = Lc[ridx[tc]];
      const bf16x8 b1 = Lc[ridx[tc] ^ 4];
      const int jb = jb0 + tc * 16;
      if (__builtin_expect((jb < hi) && (jb + 16 > lo), 0)) {  // slow path
        const int ctj = ts[jb + m];
#pragma unroll
        for (int tr = 0; tr < 4; ++tr) {
          f32x4 acc = __builtin_amdgcn_mfma_f32_16x16x32_bf16(a[tr][0], b0, fz, 0, 0, 0);
          acc = __builtin_amdgcn_mfma_f32_16x16x32_bf16(a[tr][1], b1, acc, 0, 0, 0);
#pragma unroll
          for (int r = 0; r < 4; ++r) {
            const bool  pos = (ctj == ((tpack[tr] >> (8 * r)) & 0xff));
            const float d   = acc[r];
            mp[tr * 4 + r] = fminf(mp[tr * 4 + r], pos ? d : __builtin_inff());
            mn[tr * 4 + r] = fmaxf(mn[tr * 4 + r], pos ? -__builtin_inff() : d);
          }
        }
      } else {                                      // pure-negative fast path
#pragma unroll
        for (int tr = 0; tr < 4; ++tr) {
          f32x4 acc = __builtin_amdgcn_mfma_f32_16x16x32_bf16(a[tr][0], b0, fz, 0, 0, 0);
          acc = __builtin_amdgcn_mfma_f32_16x16x32_bf16(a[tr][1], b1, acc, 0, 0, 0);
#pragma unroll
          for (int r = 0; r < 4; ++r)
            mn[tr * 4 + r] = fmaxf(mn[tr * 4 + r], acc[r]);
        }
      }
    }
    if (it < 7) {
      Ln[widx] = r0; Ln[widx + 256] = r1;           // safe: Ln last read at it-1
      __syncthreads();
    }
  }

  // reduce across the 16 m-lanes inside each q-group
#pragma unroll
  for (int s = 1; s < 16; s <<= 1) {
#pragma unroll
    for (int k = 0; k < 16; ++k) {
      mp[k] = fminf(mp[k], __shfl_xor(mp[k], s, 64));
      mn[k] = fmaxf(mn[k], __shfl_xor(mn[k], s, 64));
    }
  }
  if (m == 0) {
#pragma unroll
    for (int tr = 0; tr < 4; ++tr)
#pragma unroll
      for (int r = 0; r < 4; ++r) {
        const int row = rowbase + tr * 16 + q * 4 + r;
        atomicMin(&mp_key[row], enc_key(mp[tr * 4 + r]));
        atomicMax(&mn_key[row], enc_key(mn[tr * 4 + r]));
      }
  }

  // ---- fused finalize: last block to finish reduces everything ----
  __threadfence();
  if (tid == 0) is_last = (atomicAdd(done, 1u) == (unsigned)(gridDim.x - 1));
  __syncthreads();
  if (is_last) {
    float s1 = 0.f;
    for (int r = tid; r < N_ROWS; r += 256) {
      const unsigned kp = __hip_atomic_load(&mp_key[r], __ATOMIC_RELAXED, __HIP_MEMORY_SCOPE_AGENT);
      const unsigned kn = __hip_atomic_load(&mn_key[r], __ATOMIC_RELAXED, __HIP_MEMORY_SCOPE_AGENT);
      const float ap = dec_key(kp);
      const float an = dec_key(kn);
      s1 += fmaxf(0.5f + ap - an, 0.f) + fmaxf(0.8f - ap, 0.f) + fmaxf(an - 0.4f, 0.f)
          + ce_row[r];
    }
#pragma unroll
    for (int d = 1; d < 64; d <<= 1) s1 += __shfl_xor(s1, d, 64);
    if (lane == 0) red[wv] = s1;
    __syncthreads();
    if (tid == 0)
      out[0] = (red[0] + red[1] + red[2] + red[3]) * (1.0f / N_ROWS);
  }
}

extern "C" void kernel_launch(void* const* d_in, const int* in_sizes, int n_in,
                              void* d_out, int out_size, void* d_ws, size_t ws_size,
                              hipStream_t stream) {
  const float* x   = (const float*)d_in[0];
  const int*   tgt = (const int*)d_in[1];
  char* ws = (char*)d_ws;

  unsigned short* xs     = (unsigned short*)ws;                           // 2 MB sorted bf16
  unsigned*       mp_key = (unsigned*)(ws + (2u << 20));                  // 64 KB
  unsigned*       mn_key = (unsigned*)(ws + (2u << 20) + (64u << 10));    // 64 KB
  float*          ce_row = (float*)(ws + (2u << 20) + (128u << 10));      // 64 KB
  int*            ts     = (int*)(ws + (2u << 20) + (192u << 10));        // 64 KB
  int*            cstart = (int*)(ws + (2u << 20) + (256u << 10));        // 65*4 B (pad 1KB)
  int*            hist   = (int*)(ws + (2u << 20) + (257u << 10));        // 256 B
  int*            cursor = (int*)(ws + (2u << 20) + (257u << 10) + 256);  // 256 B
  unsigned*       done   = (unsigned*)(ws + (2u << 20) + (257u << 10) + 512); // 4 B
  float*          out    = (float*)d_out;

  // zero hist + cursor + done in one node
  hipMemsetAsync(hist, 0, 1024, stream);

  hist_kernel<<<64, 256, 0, stream>>>(tgt, hist, mp_key, mn_key);
  prep_kernel<<<1024, 256, 0, stream>>>(x, tgt, hist, cursor, cstart, xs, ts, ce_row);
  mine_kernel<<<2048, 256, 0, stream>>>(xs, ts, cstart, ce_row, mp_key, mn_key, done, out);
}